// Round 1
// baseline (916.646 us; speedup 1.0000x reference)
//
#include <hip/hip_runtime.h>
#include <math.h>

#define NN 50000
#define NE 800000
#define HD 128
#define NH 8
#define DO 16
#define NEG_BIG -3.0e38f

// ---------------- init: zero degree counters ----------------
__global__ void init_kernel(int* __restrict__ indeg) {
    int i = blockIdx.x * blockDim.x + threadIdx.x;
    if (i < NN) indeg[i] = 0;
}

// ---------------- count in-degrees ----------------
__global__ void count_deg_kernel(const int* __restrict__ dst, int* __restrict__ indeg) {
    int e = blockIdx.x * blockDim.x + threadIdx.x;
    if (e < NE) atomicAdd(&indeg[dst[e]], 1);
}

// ---------------- exclusive scan (single block, 1024 threads) ----------------
__global__ __launch_bounds__(1024) void scan_kernel(const int* __restrict__ indeg,
                                                    int* __restrict__ offsets,
                                                    int* __restrict__ cursor) {
    __shared__ int part[1024];
    const int t = threadIdx.x;
    const int CH = (NN + 1023) / 1024; // 49
    int b = t * CH, e = min(b + CH, NN);
    int s = 0;
    for (int i = b; i < e; ++i) s += indeg[i];
    part[t] = s;
    __syncthreads();
    for (int off = 1; off < 1024; off <<= 1) {
        int v = (t >= off) ? part[t - off] : 0;
        __syncthreads();
        part[t] += v;
        __syncthreads();
    }
    int base = (t == 0) ? 0 : part[t - 1];
    for (int i = b; i < e; ++i) {
        offsets[i] = base;
        cursor[i] = base;
        base += indeg[i];
    }
    if (t == 1023) offsets[NN] = base;
}

// ---------------- scatter edges into CSR order ----------------
__global__ void scatter_kernel(const int* __restrict__ src, const int* __restrict__ dst,
                               int* __restrict__ cursor, int2* __restrict__ sorted) {
    int e = blockIdx.x * blockDim.x + threadIdx.x;
    if (e < NE) {
        int d = dst[e];
        int pos = atomicAdd(&cursor[d], 1);
        sorted[pos] = make_int2(src[e], e);
    }
}

// ---------------- register-tiled GEMM: out[M,128] (+)= A[M,128] @ W[128,128] ----------------
// 256 threads, 32 rows/block, each thread computes 2 rows x 8 cols.
// W (64KB) + XOR-swizzled A tile (16KB) in LDS -> conflict-free reads, 2 blocks/CU.
// FUSE_ATTN: also emit el/er = einsum(h, attn_l/r) from the accumulators.
template<bool FUSE_ATTN, bool ADD>
__global__ __launch_bounds__(256) void gemm128_kernel(
    const float* __restrict__ A, const float* __restrict__ W,
    float* __restrict__ out,
    const float* __restrict__ attn_l, const float* __restrict__ attn_r,
    float* __restrict__ el, float* __restrict__ er)
{
    __shared__ float sW[HD * HD];   // 64 KB
    __shared__ float sA[32 * HD];   // 16 KB
    const int tid = threadIdx.x;
    float4* sWv = (float4*)sW;
    float4* sAv = (float4*)sA;
    const float4* Wv = (const float4*)W;
    for (int j = tid; j < HD * 32; j += 256) sWv[j] = Wv[j];

    const int tc = tid & 15;          // cols 8*tc .. 8*tc+7
    const int tr = tid >> 4;          // rows 2*tr, 2*tr+1
    const int ra = 2 * tr, rb = ra + 1;
    const int sx = (tr & 3) << 3;     // XOR swizzle (float index) shared by both rows
    const float4* Av = (const float4*)A;

    for (int row0 = blockIdx.x * 32; row0 < NN; row0 += gridDim.x * 32) {
        __syncthreads();
#pragma unroll
        for (int j = 0; j < 4; ++j) {
            int f = tid + j * 256;
            int rr = f >> 5, c4 = f & 31;
            int gr = row0 + rr;
            float4 v = make_float4(0.f, 0.f, 0.f, 0.f);
            if (gr < NN) v = Av[(size_t)gr * 32 + c4];
            sAv[rr * 32 + (c4 ^ (((rr >> 1) & 3) << 1))] = v;
        }
        __syncthreads();

        float4 a00 = make_float4(0.f,0.f,0.f,0.f), a01 = a00, a10 = a00, a11 = a00;
#pragma unroll 4
        for (int k = 0; k < HD; ++k) {
            float4 w0 = sWv[k * 32 + 2 * tc];
            float4 w1 = sWv[k * 32 + 2 * tc + 1];
            float xa = sA[ra * HD + (k ^ sx)];
            float xb = sA[rb * HD + (k ^ sx)];
            a00.x = fmaf(xa, w0.x, a00.x); a00.y = fmaf(xa, w0.y, a00.y);
            a00.z = fmaf(xa, w0.z, a00.z); a00.w = fmaf(xa, w0.w, a00.w);
            a01.x = fmaf(xa, w1.x, a01.x); a01.y = fmaf(xa, w1.y, a01.y);
            a01.z = fmaf(xa, w1.z, a01.z); a01.w = fmaf(xa, w1.w, a01.w);
            a10.x = fmaf(xb, w0.x, a10.x); a10.y = fmaf(xb, w0.y, a10.y);
            a10.z = fmaf(xb, w0.z, a10.z); a10.w = fmaf(xb, w0.w, a10.w);
            a11.x = fmaf(xb, w1.x, a11.x); a11.y = fmaf(xb, w1.y, a11.y);
            a11.z = fmaf(xb, w1.z, a11.z); a11.w = fmaf(xb, w1.w, a11.w);
        }

        const int ga = row0 + ra, gb = row0 + rb;

        if (FUSE_ATTN) {
            // thread's 8 cols live inside one head: h = tc>>1, d-offset = (tc&1)*8
            const int hh = tc >> 1;
            const int db = (tc & 1) << 3;
            const float* al  = attn_l + hh * DO + db;
            const float* arr = attn_r + hh * DO + db;
            float sl_a = a00.x*al[0] + a00.y*al[1] + a00.z*al[2] + a00.w*al[3]
                       + a01.x*al[4] + a01.y*al[5] + a01.z*al[6] + a01.w*al[7];
            float sr_a = a00.x*arr[0] + a00.y*arr[1] + a00.z*arr[2] + a00.w*arr[3]
                       + a01.x*arr[4] + a01.y*arr[5] + a01.z*arr[6] + a01.w*arr[7];
            float sl_b = a10.x*al[0] + a10.y*al[1] + a10.z*al[2] + a10.w*al[3]
                       + a11.x*al[4] + a11.y*al[5] + a11.z*al[6] + a11.w*al[7];
            float sr_b = a10.x*arr[0] + a10.y*arr[1] + a10.z*arr[2] + a10.w*arr[3]
                       + a11.x*arr[4] + a11.y*arr[5] + a11.z*arr[6] + a11.w*arr[7];
            sl_a += __shfl_xor(sl_a, 1);  sr_a += __shfl_xor(sr_a, 1);
            sl_b += __shfl_xor(sl_b, 1);  sr_b += __shfl_xor(sr_b, 1);
            if (!(tc & 1)) {
                if (ga < NN) { el[ga * NH + hh] = sl_a; er[ga * NH + hh] = sr_a; }
                if (gb < NN) { el[gb * NH + hh] = sl_b; er[gb * NH + hh] = sr_b; }
            }
        }

        float4* outv = (float4*)out;
        if (ga < NN) {
            size_t b = (size_t)ga * 32 + 2 * tc;
            if (ADD) {
                float4 p0 = outv[b], p1 = outv[b + 1];
                p0.x += a00.x; p0.y += a00.y; p0.z += a00.z; p0.w += a00.w;
                p1.x += a01.x; p1.y += a01.y; p1.z += a01.z; p1.w += a01.w;
                outv[b] = p0; outv[b + 1] = p1;
            } else {
                outv[b] = a00; outv[b + 1] = a01;
            }
        }
        if (gb < NN) {
            size_t b = (size_t)gb * 32 + 2 * tc;
            if (ADD) {
                float4 p0 = outv[b], p1 = outv[b + 1];
                p0.x += a10.x; p0.y += a10.y; p0.z += a10.z; p0.w += a10.w;
                p1.x += a11.x; p1.y += a11.y; p1.z += a11.z; p1.w += a11.w;
                outv[b] = p0; outv[b + 1] = p1;
            } else {
                outv[b] = a10; outv[b + 1] = a11;
            }
        }
    }
}

// ---------------- fused per-node GAT: one wave per node, no atomics ----------------
// Slimmed: W_e GEMV hoisted out; writes partial out + scaled edge aggregate.
__global__ __launch_bounds__(256) void node_kernel(
    const int2* __restrict__ sorted, const int* __restrict__ offsets,
    const float* __restrict__ hf, const float* __restrict__ efeat,
    const float* __restrict__ el, const float* __restrict__ er,
    const float* __restrict__ bias, const float* __restrict__ b_e,
    float* __restrict__ out, float* __restrict__ eaggs)
{
    int wv   = threadIdx.x >> 6;
    int lane = threadIdx.x & 63;
    int node = blockIdx.x * 4 + wv;
    if (node >= NN) return;
    int beg = offsets[node];
    int end = offsets[node + 1];

    // ---- pass 1: online softmax stats; lane = esub*8 + h ----
    int h = lane & 7;
    float er_h = er[node * NH + h];
    float m = NEG_BIG, ssum = 0.0f;
    for (int i = beg + (lane >> 3); i < end; i += 8) {
        int s = sorted[i].x;
        float x = el[s * NH + h] + er_h;
        x = x > 0.0f ? x : 0.2f * x;
        if (x > m) { ssum = ssum * __expf(m - x) + 1.0f; m = x; }
        else        ssum += __expf(x - m);
    }
#pragma unroll
    for (int off = 8; off < 64; off <<= 1) {
        float mo = __shfl_xor(m, off);
        float so = __shfl_xor(ssum, off);
        float mn = fmaxf(m, mo);
        ssum = ssum * __expf(m - mn) + so * __expf(mo - mn);
        m = mn;
    }
    float r = ssum > 0.0f ? 1.0f / ssum : 0.0f;

    // ---- pass 2: weighted hf gather + efeat sum, cols c1=lane, c2=lane+64 ----
    int h1 = lane >> 4;
    int h2 = h1 + 4;
    float m1 = __shfl(m, h1), r1 = __shfl(r, h1);
    float m2 = __shfl(m, h2), r2 = __shfl(r, h2);
    float er1 = er[node * NH + h1];
    float er2 = er[node * NH + h2];

    float acc0 = 0.0f, acc1 = 0.0f, ea0 = 0.0f, ea1 = 0.0f;
#pragma unroll 4
    for (int i = beg; i < end; ++i) {
        int2 se = sorted[i];
        int s = se.x;
        size_t eb = (size_t)se.y * HD;
        float x1 = el[s * NH + h1] + er1; x1 = x1 > 0.0f ? x1 : 0.2f * x1;
        float x2 = el[s * NH + h2] + er2; x2 = x2 > 0.0f ? x2 : 0.2f * x2;
        float w1 = __expf(x1 - m1) * r1;
        float w2 = __expf(x2 - m2) * r2;
        acc0 += w1 * hf[(size_t)s * HD + lane];
        acc1 += w2 * hf[(size_t)s * HD + lane + 64];
        ea0 += efeat[eb + lane];
        ea1 += efeat[eb + lane + 64];
    }

    // ---- epilogue: partial out (GAT + bias + skip + b_e term) and scaled eagg ----
    float deg  = (float)(end - beg);
    float rdeg = 1.0f / fmaxf(deg, 1.0f);
    float rskip = 1.0f / (deg + 1.0f);
    float bsel = deg > 0.0f ? 1.0f : 0.0f;
    size_t o = (size_t)node * HD;
    out[o + lane]      = acc0 + bias[lane]      + hf[o + lane]      * rskip + bsel * b_e[lane];
    out[o + lane + 64] = acc1 + bias[lane + 64] + hf[o + lane + 64] * rskip + bsel * b_e[lane + 64];
    eaggs[o + lane]      = ea0 * rdeg;
    eaggs[o + lane + 64] = ea1 * rdeg;
}

extern "C" void kernel_launch(void* const* d_in, const int* in_sizes, int n_in,
                              void* d_out, int out_size, void* d_ws, size_t ws_size,
                              hipStream_t stream) {
    const float* nfeat  = (const float*)d_in[0];
    const float* efeat  = (const float*)d_in[1];
    const int*   src    = (const int*)d_in[2];
    const int*   dst    = (const int*)d_in[3];
    const float* W_fc   = (const float*)d_in[4];
    const float* attn_l = (const float*)d_in[5];
    const float* attn_r = (const float*)d_in[6];
    const float* bias   = (const float*)d_in[7];
    const float* W_e    = (const float*)d_in[8];
    const float* b_e    = (const float*)d_in[9];
    float* out = (float*)d_out;

    // workspace layout (~62 MB)
    float* ws = (float*)d_ws;
    size_t o = 0;
    float* hf      = ws + o; o += (size_t)NN * HD;       // 25.6 MB
    float* el      = ws + o; o += (size_t)NN * NH;
    float* er      = ws + o; o += (size_t)NN * NH;
    int*   indeg   = (int*)(ws + o); o += NN;
    int*   offsets = (int*)(ws + o); o += NN + 1;
    int*   cursor  = (int*)(ws + o); o += NN;
    o = (o + 1) & ~(size_t)1;
    int2*  sorted  = (int2*)(ws + o); o += (size_t)NE * 2; // 6.4 MB
    float* eaggs   = ws + o; o += (size_t)NN * HD;         // 25.6 MB

    init_kernel<<<(NN + 255) / 256, 256, 0, stream>>>(indeg);
    count_deg_kernel<<<(NE + 255) / 256, 256, 0, stream>>>(dst, indeg);
    scan_kernel<<<1, 1024, 0, stream>>>(indeg, offsets, cursor);
    scatter_kernel<<<(NE + 255) / 256, 256, 0, stream>>>(src, dst, cursor, sorted);

    // hf = nfeat @ W_fc, fused el/er projection
    gemm128_kernel<true, false><<<(NN + 31) / 32, 256, 0, stream>>>(
        nfeat, W_fc, hf, attn_l, attn_r, el, er);

    // GAT aggregation + skip + bias + b_e term -> out; scaled efeat sums -> eaggs
    node_kernel<<<(NN + 3) / 4, 256, 0, stream>>>(sorted, offsets, hf, efeat,
                                                  el, er, bias, b_e, out, eaggs);

    // out += eaggs @ W_e   (hoisted econv GEMM)
    gemm128_kernel<false, true><<<(NN + 31) / 32, 256, 0, stream>>>(
        eaggs, W_e, out, nullptr, nullptr, nullptr, nullptr);
}

// Round 2
// 881.124 us; speedup vs baseline: 1.0403x; 1.0403x over previous
//
#include <hip/hip_runtime.h>
#include <math.h>

#define NN 50000
#define NE 800000
#define HD 128
#define NH 8
#define DO 16
#define NEG_BIG -3.0e38f

__device__ inline void fma4(float4& a, float s, const float4& b) {
    a.x = fmaf(s, b.x, a.x); a.y = fmaf(s, b.y, a.y);
    a.z = fmaf(s, b.z, a.z); a.w = fmaf(s, b.w, a.w);
}
__device__ inline void red4(float4& a, int off) {
    a.x += __shfl_xor(a.x, off); a.y += __shfl_xor(a.y, off);
    a.z += __shfl_xor(a.z, off); a.w += __shfl_xor(a.w, off);
}

// ---------------- init: zero degree counters ----------------
__global__ void init_kernel(int* __restrict__ indeg) {
    int i = blockIdx.x * blockDim.x + threadIdx.x;
    if (i < NN) indeg[i] = 0;
}

// ---------------- count in-degrees ----------------
__global__ void count_deg_kernel(const int* __restrict__ dst, int* __restrict__ indeg) {
    int e = blockIdx.x * blockDim.x + threadIdx.x;
    if (e < NE) atomicAdd(&indeg[dst[e]], 1);
}

// ---------------- exclusive scan (single block, 1024 threads) ----------------
__global__ __launch_bounds__(1024) void scan_kernel(const int* __restrict__ indeg,
                                                    int* __restrict__ offsets,
                                                    int* __restrict__ cursor) {
    __shared__ int part[1024];
    const int t = threadIdx.x;
    const int CH = (NN + 1023) / 1024; // 49
    int b = t * CH, e = min(b + CH, NN);
    int s = 0;
    for (int i = b; i < e; ++i) s += indeg[i];
    part[t] = s;
    __syncthreads();
    for (int off = 1; off < 1024; off <<= 1) {
        int v = (t >= off) ? part[t - off] : 0;
        __syncthreads();
        part[t] += v;
        __syncthreads();
    }
    int base = (t == 0) ? 0 : part[t - 1];
    for (int i = b; i < e; ++i) {
        offsets[i] = base;
        cursor[i] = base;
        base += indeg[i];
    }
    if (t == 1023) offsets[NN] = base;
}

// ---------------- scatter edges into CSR order ----------------
__global__ void scatter_kernel(const int* __restrict__ src, const int* __restrict__ dst,
                               int* __restrict__ cursor, int2* __restrict__ sorted) {
    int e = blockIdx.x * blockDim.x + threadIdx.x;
    if (e < NE) {
        int d = dst[e];
        int pos = atomicAdd(&cursor[d], 1);
        sorted[pos] = make_int2(src[e], e);
    }
}

// ---------------- GEMM: out[M,128] (+)= A[M,128] @ W[128,128] ----------------
// 256 threads, 64 rows/block. Thread (tc,tr): cols {4tc..4tc+3, 4tc+64..+67},
// rows {tr, tr+16, tr+32, tr+48}. LDS: sA 32KB (row-XOR swizzled) + sW 16KB
// K-chunk => 48KB -> 3 blocks/CU. sW read: groups tc / tc+16 -> 2-way alias (free).
// sA read: 4 distinct banks via XOR-by-(row&3) (free).
template<bool FUSE_ATTN, bool ADD>
__global__ __launch_bounds__(256, 3) void gemm64_kernel(
    const float* __restrict__ A, const float* __restrict__ W,
    float* __restrict__ out,
    const float* __restrict__ attn_l, const float* __restrict__ attn_r,
    float* __restrict__ el, float* __restrict__ er)
{
    __shared__ float sA[64 * HD];   // 32 KB
    __shared__ float sW[32 * HD];   // 16 KB (one K-chunk)
    const int tid = threadIdx.x;
    const int tc = tid & 15;
    const int tr = tid >> 4;
    const int row0 = blockIdx.x * 64;

    // stage A tile, XOR-swizzle float4-group by (row&3)<<1
    const float4* Av = (const float4*)A;
    float4* sAv = (float4*)sA;
#pragma unroll
    for (int j = 0; j < 8; ++j) {
        int f = tid + j * 256;          // 0..2047
        int r = f >> 5, g = f & 31;
        int gr = row0 + r;
        float4 v = make_float4(0.f, 0.f, 0.f, 0.f);
        if (gr < NN) v = Av[(size_t)gr * 32 + g];
        sAv[r * 32 + (g ^ ((r & 3) << 1))] = v;
    }

    float4 acc[4][2];
#pragma unroll
    for (int rj = 0; rj < 4; ++rj) {
        acc[rj][0] = make_float4(0.f, 0.f, 0.f, 0.f);
        acc[rj][1] = make_float4(0.f, 0.f, 0.f, 0.f);
    }

    const float4* Wv = (const float4*)W;
    float4* sWv = (float4*)sW;
    for (int kc = 0; kc < 4; ++kc) {
        __syncthreads();
#pragma unroll
        for (int j = 0; j < 4; ++j) {
            int f = tid + j * 256;      // 0..1023 : row kk=f>>5, group g=f&31
            sWv[f] = Wv[(size_t)(kc * 32 + (f >> 5)) * 32 + (f & 31)];
        }
        __syncthreads();
#pragma unroll 8
        for (int kk = 0; kk < 32; ++kk) {
            float4 w0 = sWv[kk * 32 + tc];
            float4 w1 = sWv[kk * 32 + 16 + tc];
            int k = kc * 32 + kk;
#pragma unroll
            for (int rj = 0; rj < 4; ++rj) {
                int r = tr + rj * 16;
                float a = sA[r * HD + (k ^ ((r & 3) << 3))];
                fma4(acc[rj][0], a, w0);
                fma4(acc[rj][1], a, w1);
            }
        }
    }

    if (FUSE_ATTN) {
        // cols 4tc.. live in head h1=tc>>2 at d=4q.. (q=tc&3); +64 cols in head h1+4
        const int h1 = tc >> 2, q = tc & 3;
        float4 al0 = ((const float4*)attn_l)[h1 * 4 + q];
        float4 ar0 = ((const float4*)attn_r)[h1 * 4 + q];
        float4 al1 = ((const float4*)attn_l)[(h1 + 4) * 4 + q];
        float4 ar1 = ((const float4*)attn_r)[(h1 + 4) * 4 + q];
#pragma unroll
        for (int rj = 0; rj < 4; ++rj) {
            float sl0 = acc[rj][0].x * al0.x + acc[rj][0].y * al0.y + acc[rj][0].z * al0.z + acc[rj][0].w * al0.w;
            float sr0 = acc[rj][0].x * ar0.x + acc[rj][0].y * ar0.y + acc[rj][0].z * ar0.z + acc[rj][0].w * ar0.w;
            float sl1 = acc[rj][1].x * al1.x + acc[rj][1].y * al1.y + acc[rj][1].z * al1.z + acc[rj][1].w * al1.w;
            float sr1 = acc[rj][1].x * ar1.x + acc[rj][1].y * ar1.y + acc[rj][1].z * ar1.z + acc[rj][1].w * ar1.w;
            sl0 += __shfl_xor(sl0, 1); sl0 += __shfl_xor(sl0, 2);
            sr0 += __shfl_xor(sr0, 1); sr0 += __shfl_xor(sr0, 2);
            sl1 += __shfl_xor(sl1, 1); sl1 += __shfl_xor(sl1, 2);
            sr1 += __shfl_xor(sr1, 1); sr1 += __shfl_xor(sr1, 2);
            int gr = row0 + tr + rj * 16;
            if (q == 0 && gr < NN) {
                el[gr * NH + h1]     = sl0;  er[gr * NH + h1]     = sr0;
                el[gr * NH + h1 + 4] = sl1;  er[gr * NH + h1 + 4] = sr1;
            }
        }
    }

    float4* outv = (float4*)out;
#pragma unroll
    for (int rj = 0; rj < 4; ++rj) {
        int gr = row0 + tr + rj * 16;
        if (gr < NN) {
            size_t b = (size_t)gr * 32;
            if (ADD) {
                float4 p0 = outv[b + tc], p1 = outv[b + 16 + tc];
                p0.x += acc[rj][0].x; p0.y += acc[rj][0].y; p0.z += acc[rj][0].z; p0.w += acc[rj][0].w;
                p1.x += acc[rj][1].x; p1.y += acc[rj][1].y; p1.z += acc[rj][1].z; p1.w += acc[rj][1].w;
                outv[b + tc] = p0; outv[b + 16 + tc] = p1;
            } else {
                outv[b + tc] = acc[rj][0];
                outv[b + 16 + tc] = acc[rj][1];
            }
        }
    }
}

// ---------------- fused per-node GAT: one wave per node ----------------
// pass 2 transposed: lane = eslot(0..3)*16 + cg(0..15); 4 edges/iter, float4 loads.
__global__ __launch_bounds__(256) void node_kernel(
    const int2* __restrict__ sorted, const int* __restrict__ offsets,
    const float* __restrict__ hf, const float* __restrict__ efeat,
    const float* __restrict__ el, const float* __restrict__ er,
    const float* __restrict__ bias, const float* __restrict__ b_e,
    float* __restrict__ out, float* __restrict__ eaggs)
{
    int wv   = threadIdx.x >> 6;
    int lane = threadIdx.x & 63;
    int node = blockIdx.x * 4 + wv;
    if (node >= NN) return;
    int beg = offsets[node];
    int end = offsets[node + 1];

    // ---- pass 1: online softmax stats; lane = esub*8 + h ----
    int h = lane & 7;
    float er_h = er[node * NH + h];
    float m = NEG_BIG, ssum = 0.0f;
    for (int i = beg + (lane >> 3); i < end; i += 8) {
        int s = sorted[i].x;
        float x = el[s * NH + h] + er_h;
        x = x > 0.0f ? x : 0.2f * x;
        if (x > m) { ssum = ssum * __expf(m - x) + 1.0f; m = x; }
        else        ssum += __expf(x - m);
    }
#pragma unroll
    for (int off = 8; off < 64; off <<= 1) {
        float mo = __shfl_xor(m, off);
        float so = __shfl_xor(ssum, off);
        float mn = fmaxf(m, mo);
        ssum = ssum * __expf(m - mn) + so * __expf(mo - mn);
        m = mn;
    }
    float r = ssum > 0.0f ? 1.0f / ssum : 0.0f;
    // lane k (k<8) now holds (m,r) for head k

    // ---- pass 2: transposed. cols {4cg..4cg+3} (head h1) and {+64} (head h2) ----
    const int eslot = lane >> 4;
    const int cg    = lane & 15;
    const int h1 = cg >> 2, h2 = h1 + 4;
    float m1 = __shfl(m, h1), r1 = __shfl(r, h1);
    float m2 = __shfl(m, h2), r2 = __shfl(r, h2);
    float er1 = er[node * NH + h1];
    float er2 = er[node * NH + h2];

    const float4* hfv = (const float4*)hf;
    const float4* efv = (const float4*)efeat;
    float4 acc0 = make_float4(0.f,0.f,0.f,0.f), acc1 = acc0, ea0 = acc0, ea1 = acc0;

#pragma unroll 2
    for (int i0 = beg; i0 < end; i0 += 4) {
        int i = i0 + eslot;
        bool valid = i < end;
        int2 se = sorted[valid ? i : beg];
        int s = se.x;
        size_t eb = (size_t)se.y * 32;
        float x1 = el[s * NH + h1] + er1; x1 = x1 > 0.0f ? x1 : 0.2f * x1;
        float x2 = el[s * NH + h2] + er2; x2 = x2 > 0.0f ? x2 : 0.2f * x2;
        float vm = valid ? 1.0f : 0.0f;
        float w1 = __expf(x1 - m1) * r1 * vm;
        float w2 = __expf(x2 - m2) * r2 * vm;
        float4 hv0 = hfv[(size_t)s * 32 + cg];
        float4 hv1 = hfv[(size_t)s * 32 + 16 + cg];
        float4 ev0 = efv[eb + cg];
        float4 ev1 = efv[eb + 16 + cg];
        fma4(acc0, w1, hv0);
        fma4(acc1, w2, hv1);
        fma4(ea0, vm, ev0);
        fma4(ea1, vm, ev1);
    }

    // reduce across the 4 edge slots (lanes xor 16, 32)
#pragma unroll
    for (int off = 16; off < 64; off <<= 1) {
        red4(acc0, off); red4(acc1, off);
        red4(ea0, off);  red4(ea1, off);
    }

    if (eslot == 0) {
        float deg   = (float)(end - beg);
        float rdeg  = 1.0f / fmaxf(deg, 1.0f);
        float rskip = 1.0f / (deg + 1.0f);
        float bsel  = deg > 0.0f ? 1.0f : 0.0f;
        size_t ob = (size_t)node * 32;
        float4 b0  = ((const float4*)bias)[cg],     b1  = ((const float4*)bias)[16 + cg];
        float4 be0 = ((const float4*)b_e)[cg],      be1 = ((const float4*)b_e)[16 + cg];
        float4 hf0 = hfv[ob + cg],                  hf1 = hfv[ob + 16 + cg];
        float4 o0, o1, g0, g1;
        o0.x = acc0.x + b0.x + hf0.x * rskip + bsel * be0.x;
        o0.y = acc0.y + b0.y + hf0.y * rskip + bsel * be0.y;
        o0.z = acc0.z + b0.z + hf0.z * rskip + bsel * be0.z;
        o0.w = acc0.w + b0.w + hf0.w * rskip + bsel * be0.w;
        o1.x = acc1.x + b1.x + hf1.x * rskip + bsel * be1.x;
        o1.y = acc1.y + b1.y + hf1.y * rskip + bsel * be1.y;
        o1.z = acc1.z + b1.z + hf1.z * rskip + bsel * be1.z;
        o1.w = acc1.w + b1.w + hf1.w * rskip + bsel * be1.w;
        g0.x = ea0.x * rdeg; g0.y = ea0.y * rdeg; g0.z = ea0.z * rdeg; g0.w = ea0.w * rdeg;
        g1.x = ea1.x * rdeg; g1.y = ea1.y * rdeg; g1.z = ea1.z * rdeg; g1.w = ea1.w * rdeg;
        ((float4*)out)[ob + cg]        = o0;
        ((float4*)out)[ob + 16 + cg]   = o1;
        ((float4*)eaggs)[ob + cg]      = g0;
        ((float4*)eaggs)[ob + 16 + cg] = g1;
    }
}

extern "C" void kernel_launch(void* const* d_in, const int* in_sizes, int n_in,
                              void* d_out, int out_size, void* d_ws, size_t ws_size,
                              hipStream_t stream) {
    const float* nfeat  = (const float*)d_in[0];
    const float* efeat  = (const float*)d_in[1];
    const int*   src    = (const int*)d_in[2];
    const int*   dst    = (const int*)d_in[3];
    const float* W_fc   = (const float*)d_in[4];
    const float* attn_l = (const float*)d_in[5];
    const float* attn_r = (const float*)d_in[6];
    const float* bias   = (const float*)d_in[7];
    const float* W_e    = (const float*)d_in[8];
    const float* b_e    = (const float*)d_in[9];
    float* out = (float*)d_out;

    // workspace layout (~62 MB)
    float* ws = (float*)d_ws;
    size_t o = 0;
    float* hf      = ws + o; o += (size_t)NN * HD;
    float* el      = ws + o; o += (size_t)NN * NH;
    float* er      = ws + o; o += (size_t)NN * NH;
    int*   indeg   = (int*)(ws + o); o += NN;
    int*   offsets = (int*)(ws + o); o += NN + 1;
    int*   cursor  = (int*)(ws + o); o += NN;
    o = (o + 1) & ~(size_t)1;
    int2*  sorted  = (int2*)(ws + o); o += (size_t)NE * 2;
    float* eaggs   = ws + o; o += (size_t)NN * HD;

    init_kernel<<<(NN + 255) / 256, 256, 0, stream>>>(indeg);
    count_deg_kernel<<<(NE + 255) / 256, 256, 0, stream>>>(dst, indeg);
    scan_kernel<<<1, 1024, 0, stream>>>(indeg, offsets, cursor);
    scatter_kernel<<<(NE + 255) / 256, 256, 0, stream>>>(src, dst, cursor, sorted);

    // hf = nfeat @ W_fc, fused el/er projection
    gemm64_kernel<true, false><<<(NN + 63) / 64, 256, 0, stream>>>(
        nfeat, W_fc, hf, attn_l, attn_r, el, er);

    // GAT aggregation + skip + bias + b_e term -> out; scaled efeat sums -> eaggs
    node_kernel<<<(NN + 3) / 4, 256, 0, stream>>>(sorted, offsets, hf, efeat,
                                                  el, er, bias, b_e, out, eaggs);

    // out += eaggs @ W_e (hoisted econv GEMM)
    gemm64_kernel<false, true><<<(NN + 63) / 64, 256, 0, stream>>>(
        eaggs, W_e, out, nullptr, nullptr, nullptr, nullptr);
}